// Round 6
// baseline (565.279 us; speedup 1.0000x reference)
//
#include <hip/hip_runtime.h>

#define DD     256
#define NROWS  51200   // C*S
#define NPROTO 2000
#define NP2    2016    // padded to 63 tiles of 32
#define NT     63
#define NCLSS  100

typedef _Float16 h8 __attribute__((ext_vector_type(8)));
typedef float f32x16 __attribute__((ext_vector_type(16)));

// async global->LDS, 16B per lane, linear dest (wave-uniform base + lane*16)
__device__ __forceinline__ void gll16(const void* g, void* l) {
    __builtin_amdgcn_global_load_lds(
        (const __attribute__((address_space(1))) unsigned int*)g,
        (__attribute__((address_space(3))) unsigned int*)l, 16, 0, 0);
}

// ---------------------------------------------------------------------------
// p2[p] = |proto_p|^2 ; padded entries get +1e30 so logit -> -1e30
// ---------------------------------------------------------------------------
__global__ void p2_kernel(const float* __restrict__ protos, float* __restrict__ p2) {
    int p = blockIdx.x * 256 + threadIdx.x;
    if (p >= NP2) return;
    if (p >= NPROTO) { p2[p] = 1e30f; return; }
    const float4* row = reinterpret_cast<const float4*>(protos + (size_t)p * DD);
    float s = 0.f;
    #pragma unroll 8
    for (int k = 0; k < DD / 4; ++k) {
        float4 v = row[k];
        s = fmaf(v.x, v.x, s); s = fmaf(v.y, v.y, s);
        s = fmaf(v.z, v.z, s); s = fmaf(v.w, v.w, s);
    }
    p2[p] = s;
}

// ---------------------------------------------------------------------------
// Proto images (f16 hi only):
//  PHsw: per tile [32 p][32 units of 8 f16], unit u stored at u^(p&7)
//  PTsw: per tile [256 d][34 f16] (cols 0..31 = protos; 32..33 pad, unread)
// ---------------------------------------------------------------------------
__global__ __launch_bounds__(256) void prep_proto(
    const float* __restrict__ protos,
    _Float16* __restrict__ PHsw, _Float16* __restrict__ PTsw)
{
    const int id = blockIdx.x * 256 + threadIdx.x;   // 0..64511
    const int pg = id >> 5;                          // proto 0..2015
    const int u  = id & 31;
    const int tile = pg >> 5;
    const int p = pg & 31;

    float v[8];
    #pragma unroll
    for (int j = 0; j < 8; ++j) v[j] = 0.f;
    if (pg < NPROTO) {
        const float4 a = *(const float4*)(protos + (size_t)pg * DD + u * 8);
        const float4 b = *(const float4*)(protos + (size_t)pg * DD + u * 8 + 4);
        v[0]=a.x; v[1]=a.y; v[2]=a.z; v[3]=a.w;
        v[4]=b.x; v[5]=b.y; v[6]=b.z; v[7]=b.w;
    }
    h8 ph;
    #pragma unroll
    for (int j = 0; j < 8; ++j) ph[j] = (_Float16)v[j];
    *(h8*)(PHsw + (size_t)tile * 8192 + p * 256 + (u ^ (p & 7)) * 8) = ph;
    _Float16* pt = PTsw + (size_t)tile * 8704;
    #pragma unroll
    for (int j = 0; j < 8; ++j)
        pt[(u * 8 + j) * 34 + p] = ph[j];
}

// ---------------------------------------------------------------------------
// WHsw: 8 tiles x [32 cols][32 units], B[k][c]=W[c][k], unit u at u^(c&7)
// ---------------------------------------------------------------------------
__global__ __launch_bounds__(256) void prep_w(
    const float* __restrict__ W, _Float16* __restrict__ WHsw)
{
    const int id = blockIdx.x * 256 + threadIdx.x;   // 0..8191
    const int c = id >> 5;                           // 0..255
    const int u = id & 31;
    const float4 a = *(const float4*)(W + (size_t)c * DD + u * 8);
    const float4 b = *(const float4*)(W + (size_t)c * DD + u * 8 + 4);
    h8 hv;
    hv[0]=(_Float16)a.x; hv[1]=(_Float16)a.y; hv[2]=(_Float16)a.z; hv[3]=(_Float16)a.w;
    hv[4]=(_Float16)b.x; hv[5]=(_Float16)b.y; hv[6]=(_Float16)b.z; hv[7]=(_Float16)b.w;
    *(h8*)(WHsw + (size_t)(c >> 5) * 8192 + (c & 31) * 256 + ((u ^ (c & 7)) * 8)) = hv;
}

// ---------------------------------------------------------------------------
// OWsw: 8 chunks (ct 0..3 x kh 0..1) x [32 cols][32 units]; cols 100..127 zero
// ---------------------------------------------------------------------------
__global__ __launch_bounds__(256) void prep_ow(
    const float* __restrict__ OW, _Float16* __restrict__ OWsw)
{
    const int id = blockIdx.x * 256 + threadIdx.x;   // 0..8191
    const int c = id >> 6;                           // 0..127
    const int u = id & 63;                           // 0..63
    float v[8];
    #pragma unroll
    for (int j = 0; j < 8; ++j) v[j] = 0.f;
    if (c < NCLSS) {
        const float4 a = *(const float4*)(OW + (size_t)c * 512 + u * 8);
        const float4 b = *(const float4*)(OW + (size_t)c * 512 + u * 8 + 4);
        v[0]=a.x; v[1]=a.y; v[2]=a.z; v[3]=a.w;
        v[4]=b.x; v[5]=b.y; v[6]=b.z; v[7]=b.w;
    }
    h8 hv;
    #pragma unroll
    for (int j = 0; j < 8; ++j) hv[j] = (_Float16)v[j];
    const int chunk = (c >> 5) * 2 + (u >> 5);
    const int u5 = u & 31;
    *(h8*)(OWsw + (size_t)chunk * 8192 + (c & 31) * 256 + ((u5 ^ (c & 7)) * 8)) = hv;
}

// ---------------------------------------------------------------------------
// hidden: XH = f16(relu(samples @ W^T + b)), MFMA 32x32x16, 4 waves x 32 rows
// ---------------------------------------------------------------------------
__global__ __launch_bounds__(256, 2) void hidden_kernel(
    const float* __restrict__ A, const _Float16* __restrict__ WHsw,
    const float* __restrict__ bias, _Float16* __restrict__ XH)
{
    __shared__ __align__(16) _Float16 sW[2][32 * 256];
    __shared__ float sBias[256];
    const int t = threadIdx.x;
    const int wv = t >> 6, lane = t & 63, lid = lane & 31, h = lane >> 5;
    const int rowBase = blockIdx.x * 128 + wv * 32;
    const int swz = lid & 7;

    sBias[t] = bias[t];

    h8 xa[16];
    {
        const float* arow = A + (size_t)(rowBase + lid) * DD + 8 * h;
        #pragma unroll
        for (int kc = 0; kc < 16; ++kc) {
            float4 va = *(const float4*)(arow + kc * 16);
            float4 vb = *(const float4*)(arow + kc * 16 + 4);
            h8 x;
            x[0]=(_Float16)va.x; x[1]=(_Float16)va.y; x[2]=(_Float16)va.z; x[3]=(_Float16)va.w;
            x[4]=(_Float16)vb.x; x[5]=(_Float16)vb.y; x[6]=(_Float16)vb.z; x[7]=(_Float16)vb.w;
            xa[kc] = x;
        }
    }
    #pragma unroll
    for (int i = 0; i < 4; ++i)
        gll16(WHsw + (i * 256 + t) * 8, &sW[0][(i * 256 + t) * 8]);
    __syncthreads();

    #pragma unroll
    for (int ct = 0; ct < 8; ++ct) {
        const int buf = ct & 1;
        if (ct + 1 < 8) {
            const _Float16* g = WHsw + (size_t)(ct + 1) * 8192;
            #pragma unroll
            for (int i = 0; i < 4; ++i)
                gll16(g + (i * 256 + t) * 8, &sW[buf ^ 1][(i * 256 + t) * 8]);
        }
        f32x16 c0, c1;
        #pragma unroll
        for (int r = 0; r < 16; ++r) { c0[r] = 0.f; c1[r] = 0.f; }
        const _Float16* wrow = &sW[buf][lid * 256];
        #pragma unroll
        for (int kc = 0; kc < 16; kc += 2) {
            h8 b0 = *(const h8*)(wrow + (((kc    ) * 2 + h) ^ swz) * 8);
            h8 b1 = *(const h8*)(wrow + (((kc + 1) * 2 + h) ^ swz) * 8);
            c0 = __builtin_amdgcn_mfma_f32_32x32x16_f16(xa[kc],     b0, c0, 0, 0, 0);
            c1 = __builtin_amdgcn_mfma_f32_32x32x16_f16(xa[kc + 1], b1, c1, 0, 0, 0);
        }
        const float bv = sBias[ct * 32 + lid];
        #pragma unroll
        for (int r = 0; r < 16; ++r) {
            const int n = rowBase + (r & 3) + 8 * (r >> 2) + 4 * h;
            float v = c0[r] + c1[r] + bv;
            XH[(size_t)n * DD + ct * 32 + lid] = (_Float16)fmaxf(v, 0.f);
        }
        __syncthreads();
    }
}

// ---------------------------------------------------------------------------
// MFMA flash attention, D-split wave pairs.
// Block = 256 thr / 4 waves / 64 rows. Wave wv: rows rgrp=(wv&1)*32, PV dims
// dh=(wv>>1)*128 (128 of 256). QK computed redundantly per pair (cheap) so
// each wave fits 2 waves/SIMD: acc 64 + accL 16 + S 32 (AGPR) + xa 64 + misc
// ~ 230 unified regs < 256. LDS 76K -> 2 blocks/CU; counted vmcnt(9) keeps
// next-tile staging in flight across both barriers.
// C layout: col=lane&31, row=(reg&3)+8*(reg>>2)+4*(lane>>5); A/B: k=8*(lane>>5)+i
// ---------------------------------------------------------------------------
__global__ __launch_bounds__(256, 2) void attn_kernel(
    const _Float16* __restrict__ XH, const _Float16* __restrict__ PHsw,
    const _Float16* __restrict__ PTsw, const float* __restrict__ P2,
    _Float16* __restrict__ XT)
{
    __shared__ __align__(16) _Float16 sPH[2][32 * 256];   // 32 KiB
    __shared__ __align__(16) _Float16 sPT[2][256 * 34];   // 34 KiB
    __shared__ __align__(16) _Float16 sQ[4][32 * 40];     // 10 KiB

    const int t = threadIdx.x;
    const int wv = t >> 6, lane = t & 63, lid = lane & 31, h = lane >> 5;
    const int rgrp = wv & 1, dh = wv >> 1;
    const int rowBase = blockIdx.x * 64 + rgrp * 32;
    const int swz = lid & 7;

    h8 xa[16];
    {
        const _Float16* xrow = XH + (size_t)(rowBase + lid) * DD + 8 * h;
        #pragma unroll
        for (int kc = 0; kc < 16; ++kc)
            xa[kc] = *(const h8*)(xrow + kc * 16);
    }

    f32x16 acc[4], accL;
    #pragma unroll
    for (int f = 0; f < 4; ++f)
        #pragma unroll
        for (int r = 0; r < 16; ++r) acc[f][r] = 0.f;
    #pragma unroll
    for (int r = 0; r < 16; ++r) accL[r] = 0.f;

    float m[16];
    #pragma unroll
    for (int r = 0; r < 16; ++r) m[r] = -3e38f;

    h8 ones;
    #pragma unroll
    for (int j = 0; j < 8; ++j) ones[j] = (_Float16)1.f;

    // 9 vmcnt ops per wave: 4 PH + 4 PT + 1 PT-tail (tail duplicated by all
    // waves: same src, same dest, same data -> benign)
    #define STAGE(tl, bf)                                                        \
    {                                                                            \
        const _Float16* g0 = PHsw + (size_t)(tl) * 8192;                         \
        const _Float16* g2 = PTsw + (size_t)(tl) * 8704;                         \
        _Pragma("unroll")                                                        \
        for (int i = 0; i < 4; ++i)                                              \
            gll16(g0 + (i * 256 + t) * 8, &sPH[bf][(i * 256 + t) * 8]);          \
        _Pragma("unroll")                                                        \
        for (int i = 0; i < 4; ++i)                                              \
            gll16(g2 + (i * 256 + t) * 8, &sPT[bf][(i * 256 + t) * 8]);          \
        gll16(g2 + 8192 + lane * 8, &sPT[bf][8192 + lane * 8]);                  \
    }

    STAGE(0, 0);   // prologue: tile 0 in flight

    for (int tile = 0; tile < NT; ++tile) {
        const int buf = tile & 1;
        if (tile + 1 < NT) {
            STAGE(tile + 1, buf ^ 1);
            asm volatile("s_waitcnt vmcnt(9)" ::: "memory");  // this tile landed
        } else {
            asm volatile("s_waitcnt vmcnt(0)" ::: "memory");
        }
        __builtin_amdgcn_s_barrier();

        const float p2v = P2[tile * 32 + lid];

        // ---- QK (hi only), 2 independent chains ----
        f32x16 S0, S1;
        #pragma unroll
        for (int r = 0; r < 16; ++r) { S0[r] = 0.f; S1[r] = 0.f; }
        {
            const _Float16* phrow = &sPH[buf][lid * 256];
            __builtin_amdgcn_s_setprio(1);
            #pragma unroll
            for (int kc = 0; kc < 16; kc += 2) {
                h8 b0 = *(const h8*)(phrow + (((kc    ) * 2 + h) ^ swz) * 8);
                h8 b1 = *(const h8*)(phrow + (((kc + 1) * 2 + h) ^ swz) * 8);
                S0 = __builtin_amdgcn_mfma_f32_32x32x16_f16(xa[kc],     b0, S0, 0, 0, 0);
                S1 = __builtin_amdgcn_mfma_f32_32x32x16_f16(xa[kc + 1], b1, S1, 0, 0, 0);
            }
            __builtin_amdgcn_s_setprio(0);
        }
        float S[16];
        #pragma unroll
        for (int r = 0; r < 16; ++r) S[r] = 2.f * (S0[r] + S1[r]) - p2v;

        // ---- defer-max online softmax (THR=8, f16-safe) ----
        float ex = S[0] - m[0];
        #pragma unroll
        for (int r = 1; r < 16; ++r) ex = fmaxf(ex, S[r] - m[r]);
        if (__any(ex > 8.f)) {
            float w[16];
            #pragma unroll
            for (int r = 0; r < 16; ++r) w[r] = S[r];
            #pragma unroll
            for (int msk = 1; msk < 32; msk <<= 1)
                #pragma unroll
                for (int r = 0; r < 16; ++r)
                    w[r] = fmaxf(w[r], __shfl_xor(w[r], msk, 64));
            #pragma unroll
            for (int r = 0; r < 16; ++r) {
                float mn = fmaxf(m[r], w[r]);
                float sc = __expf(m[r] - mn);
                m[r] = mn;
                #pragma unroll
                for (int f = 0; f < 4; ++f) acc[f][r] *= sc;
                accL[r] *= sc;
            }
        }
        float w[16];
        #pragma unroll
        for (int r = 0; r < 16; ++r) w[r] = __expf(S[r] - m[r]);

        // ---- q tile to own LDS region (pair waves write identical copies) ----
        {
            _Float16* q = sQ[wv];
            #pragma unroll
            for (int r = 0; r < 16; ++r) {
                const int n = (r & 3) + 8 * (r >> 2) + 4 * h;
                q[n * 40 + lid] = (_Float16)w[r];
            }
        }

        // ---- PV (own 128-dim half) + ones-column denominator ----
        {
            const _Float16* q = sQ[wv] + lid * 40 + 8 * h;
            h8 qa0 = *(const h8*)(q);
            h8 qa1 = *(const h8*)(q + 16);
            __builtin_amdgcn_s_setprio(1);
            #pragma unroll
            for (int f = 0; f < 4; ++f) {
                const _Float16* pt = &sPT[buf][(dh * 128 + f * 32 + lid) * 34 + 8 * h];
                h8 b0 = *(const h8*)(pt);
                h8 b1 = *(const h8*)(pt + 16);
                acc[f] = __builtin_amdgcn_mfma_f32_32x32x16_f16(qa0, b0, acc[f], 0, 0, 0);
                acc[f] = __builtin_amdgcn_mfma_f32_32x32x16_f16(qa1, b1, acc[f], 0, 0, 0);
            }
            accL = __builtin_amdgcn_mfma_f32_32x32x16_f16(qa0, ones, accL, 0, 0, 0);
            accL = __builtin_amdgcn_mfma_f32_32x32x16_f16(qa1, ones, accL, 0, 0, 0);
            __builtin_amdgcn_s_setprio(0);
        }
        asm volatile("s_waitcnt lgkmcnt(0)" ::: "memory");  // LDS reads retired
        __builtin_amdgcn_s_barrier();    // gate buffer overwrite next iter
    }
    #undef STAGE

    // ---- epilogue: x_tilde = acc / l (own 128-dim half) ----
    #pragma unroll
    for (int r = 0; r < 16; ++r) {
        const float inv = 1.f / accL[r];
        const int n = rowBase + (r & 3) + 8 * (r >> 2) + 4 * h;
        #pragma unroll
        for (int f = 0; f < 4; ++f)
            XT[(size_t)n * DD + dh * 128 + f * 32 + lid] = (_Float16)(acc[f][r] * inv);
    }
}

// ---------------------------------------------------------------------------
// out: OUT[n][c] = [x | x_tilde] @ OW^T, MFMA, K=512, cols padded to 128
// ---------------------------------------------------------------------------
__global__ __launch_bounds__(256, 2) void out_kernel(
    const _Float16* __restrict__ XH, const _Float16* __restrict__ XT,
    const _Float16* __restrict__ OWsw, float* __restrict__ OUT)
{
    __shared__ __align__(16) _Float16 sW[2][32 * 256];
    const int t = threadIdx.x;
    const int wv = t >> 6, lane = t & 63, lid = lane & 31, h = lane >> 5;
    const int rowBase = blockIdx.x * 128 + wv * 32;
    const int swz = lid & 7;

    h8 xa[32];
    {
        const _Float16* x0 = XH + (size_t)(rowBase + lid) * DD + 8 * h;
        const _Float16* x1 = XT + (size_t)(rowBase + lid) * DD + 8 * h;
        #pragma unroll
        for (int kc = 0; kc < 16; ++kc) xa[kc]      = *(const h8*)(x0 + kc * 16);
        #pragma unroll
        for (int kc = 0; kc < 16; ++kc) xa[16 + kc] = *(const h8*)(x1 + kc * 16);
    }

    f32x16 acc[4];
    #pragma unroll
    for (int q = 0; q < 4; ++q)
        #pragma unroll
        for (int r = 0; r < 16; ++r) acc[q][r] = 0.f;

    #pragma unroll
    for (int i = 0; i < 4; ++i)
        gll16(OWsw + (i * 256 + t) * 8, &sW[0][(i * 256 + t) * 8]);
    __syncthreads();

    #pragma unroll
    for (int ch = 0; ch < 8; ++ch) {
        const int buf = ch & 1;
        if (ch + 1 < 8) {
            const _Float16* g = OWsw + (size_t)(ch + 1) * 8192;
            #pragma unroll
            for (int i = 0; i < 4; ++i)
                gll16(g + (i * 256 + t) * 8, &sW[buf ^ 1][(i * 256 + t) * 8]);
        }
        const int ct = ch >> 1, kh = ch & 1;
        const _Float16* wrow = &sW[buf][lid * 256];
        f32x16 a = acc[ct];
        #pragma unroll
        for (int kc = 0; kc < 16; ++kc) {
            h8 b = *(const h8*)(wrow + ((kc * 2 + h) ^ swz) * 8);
            a = __builtin_amdgcn_mfma_f32_32x32x16_f16(xa[kh * 16 + kc], b, a, 0, 0, 0);
        }
        acc[ct] = a;
        __syncthreads();
    }

    #pragma unroll
    for (int ct = 0; ct < 4; ++ct) {
        const int col = ct * 32 + lid;
        if (col < NCLSS) {
            #pragma unroll
            for (int r = 0; r < 16; ++r) {
                const int n = rowBase + (r & 3) + 8 * (r >> 2) + 4 * h;
                OUT[(size_t)n * NCLSS + col] = acc[ct][r];
            }
        }
    }
}

// ---------------------------------------------------------------------------
extern "C" void kernel_launch(void* const* d_in, const int* in_sizes, int n_in,
                              void* d_out, int out_size, void* d_ws, size_t ws_size,
                              hipStream_t stream) {
    const float* samples  = (const float*)d_in[0];
    const float* hidden_w = (const float*)d_in[1];
    const float* hidden_b = (const float*)d_in[2];
    const float* protos   = (const float*)d_in[3];
    const float* output_w = (const float*)d_in[4];
    float* out = (float*)d_out;

    char* ws = (char*)d_ws;
    _Float16* XH   = (_Float16*)(ws);                  // 26,214,400
    _Float16* XT   = (_Float16*)(ws + 26214400);       // 26,214,400
    _Float16* PHsw = (_Float16*)(ws + 52428800);       // 63*8192*2 = 1,032,192
    _Float16* PTsw = (_Float16*)(ws + 53460992);       // 63*8704*2 = 1,096,704
    _Float16* WHsw = (_Float16*)(ws + 54557696);       // 131,072
    _Float16* OWsw = (_Float16*)(ws + 54688768);       // 131,072
    float*    P2   = (float*)   (ws + 54819840);       // 8,064

    p2_kernel <<<8,   256, 0, stream>>>(protos, P2);
    prep_proto<<<252, 256, 0, stream>>>(protos, PHsw, PTsw);
    prep_w    <<<32,  256, 0, stream>>>(hidden_w, WHsw);
    prep_ow   <<<32,  256, 0, stream>>>(output_w, OWsw);
    hidden_kernel<<<400, 256, 0, stream>>>(samples, WHsw, hidden_b, XH);
    attn_kernel  <<<800, 256, 0, stream>>>(XH, PHsw, PTsw, P2, XT);
    out_kernel   <<<400, 256, 0, stream>>>(XH, XT, OWsw, out);
}

// Round 8
// 222.839 us; speedup vs baseline: 2.5367x; 2.5367x over previous
//
#include <hip/hip_runtime.h>

#define DD     256
#define NROWS  51200   // C*S
#define NPROTO 2000
#define NP2    2016    // padded to 63 tiles of 32
#define NT     63
#define NCLSS  100

typedef _Float16 h8 __attribute__((ext_vector_type(8)));
typedef __fp16  fp16x2 __attribute__((ext_vector_type(2)));   // cvt_pkrtz's native type
typedef float f32x16 __attribute__((ext_vector_type(16)));

// async global->LDS, 16B per lane, linear dest (wave-uniform base + lane*16)
__device__ __forceinline__ void gll16(const void* g, void* l) {
    __builtin_amdgcn_global_load_lds(
        (const __attribute__((address_space(1))) unsigned int*)g,
        (__attribute__((address_space(3))) unsigned int*)l, 16, 0, 0);
}

// ---------------------------------------------------------------------------
// p2[p] = |proto_p|^2 ; padded entries get +1e30 (clamped to 120000 in prep)
// ---------------------------------------------------------------------------
__global__ void p2_kernel(const float* __restrict__ protos, float* __restrict__ p2) {
    int p = blockIdx.x * 256 + threadIdx.x;
    if (p >= NP2) return;
    if (p >= NPROTO) { p2[p] = 1e30f; return; }
    const float4* row = reinterpret_cast<const float4*>(protos + (size_t)p * DD);
    float s = 0.f;
    #pragma unroll 8
    for (int k = 0; k < DD / 4; ++k) {
        float4 v = row[k];
        s = fmaf(v.x, v.x, s); s = fmaf(v.y, v.y, s);
        s = fmaf(v.z, v.z, s); s = fmaf(v.w, v.w, s);
    }
    p2[p] = s;
}

// ---------------------------------------------------------------------------
// Proto images (f16 hi only), K augmented with -|p|^2/2 (hi+lo split):
//  PHsw: per tile [32 p][40 units of 8 f16]:
//    units 0..31 = proto dims, unit u stored at u^(p&7)
//    units 32..39 = aug: logical v stored at 32+(v^(p&7));
//      logical v=0 holds {-p2/2_hi, -p2/2_lo, 0...}, v>=1 zeros
//  PTsw: per tile [256 d][40 f16] (cols 0..31 = protos, 32..39 pad unread)
// ---------------------------------------------------------------------------
__global__ __launch_bounds__(256) void prep_proto(
    const float* __restrict__ protos, const float* __restrict__ P2,
    _Float16* __restrict__ PHsw, _Float16* __restrict__ PTsw)
{
    const int id = blockIdx.x * 256 + threadIdx.x;   // 0..64511
    const int pg = id >> 5;                          // proto 0..2015
    const int u  = id & 31;
    const int tile = pg >> 5;
    const int p = pg & 31;

    float v[8];
    #pragma unroll
    for (int j = 0; j < 8; ++j) v[j] = 0.f;
    if (pg < NPROTO) {
        const float4 a = *(const float4*)(protos + (size_t)pg * DD + u * 8);
        const float4 b = *(const float4*)(protos + (size_t)pg * DD + u * 8 + 4);
        v[0]=a.x; v[1]=a.y; v[2]=a.z; v[3]=a.w;
        v[4]=b.x; v[5]=b.y; v[6]=b.z; v[7]=b.w;
    }
    h8 ph;
    #pragma unroll
    for (int j = 0; j < 8; ++j) ph[j] = (_Float16)v[j];
    _Float16* phb = PHsw + (size_t)tile * 10240 + p * 320;
    *(h8*)(phb + (u ^ (p & 7)) * 8) = ph;
    if (u < 8) {
        h8 aug;
        #pragma unroll
        for (int j = 0; j < 8; ++j) aug[j] = (_Float16)0.f;
        if (u == 0) {
            float hp = fminf(P2[pg] * 0.5f, 60000.f);
            _Float16 ahi = (_Float16)(-hp);
            aug[0] = ahi;
            aug[1] = (_Float16)(-hp - (float)ahi);
        }
        *(h8*)(phb + 256 + (u ^ (p & 7)) * 8) = aug;
    }
    _Float16* pt = PTsw + (size_t)tile * 10240;
    #pragma unroll
    for (int j = 0; j < 8; ++j)
        pt[(u * 8 + j) * 40 + p] = ph[j];
}

// ---------------------------------------------------------------------------
// WHsw: 8 tiles x [32 cols][32 units], B[k][c]=W[c][k], unit u at u^(c&7)
// ---------------------------------------------------------------------------
__global__ __launch_bounds__(256) void prep_w(
    const float* __restrict__ W, _Float16* __restrict__ WHsw)
{
    const int id = blockIdx.x * 256 + threadIdx.x;   // 0..8191
    const int c = id >> 5;                           // 0..255
    const int u = id & 31;
    const float4 a = *(const float4*)(W + (size_t)c * DD + u * 8);
    const float4 b = *(const float4*)(W + (size_t)c * DD + u * 8 + 4);
    h8 hv;
    hv[0]=(_Float16)a.x; hv[1]=(_Float16)a.y; hv[2]=(_Float16)a.z; hv[3]=(_Float16)a.w;
    hv[4]=(_Float16)b.x; hv[5]=(_Float16)b.y; hv[6]=(_Float16)b.z; hv[7]=(_Float16)b.w;
    *(h8*)(WHsw + (size_t)(c >> 5) * 8192 + (c & 31) * 256 + ((u ^ (c & 7)) * 8)) = hv;
}

// ---------------------------------------------------------------------------
// OWsw: 8 chunks (ct 0..3 x kh 0..1) x [32 cols][32 units]; cols 100..127 zero
// ---------------------------------------------------------------------------
__global__ __launch_bounds__(256) void prep_ow(
    const float* __restrict__ OW, _Float16* __restrict__ OWsw)
{
    const int id = blockIdx.x * 256 + threadIdx.x;   // 0..8191
    const int c = id >> 6;                           // 0..127
    const int u = id & 63;                           // 0..63
    float v[8];
    #pragma unroll
    for (int j = 0; j < 8; ++j) v[j] = 0.f;
    if (c < NCLSS) {
        const float4 a = *(const float4*)(OW + (size_t)c * 512 + u * 8);
        const float4 b = *(const float4*)(OW + (size_t)c * 512 + u * 8 + 4);
        v[0]=a.x; v[1]=a.y; v[2]=a.z; v[3]=a.w;
        v[4]=b.x; v[5]=b.y; v[6]=b.z; v[7]=b.w;
    }
    h8 hv;
    #pragma unroll
    for (int j = 0; j < 8; ++j) hv[j] = (_Float16)v[j];
    const int chunk = (c >> 5) * 2 + (u >> 5);
    const int u5 = u & 31;
    *(h8*)(OWsw + (size_t)chunk * 8192 + (c & 31) * 256 + ((u5 ^ (c & 7)) * 8)) = hv;
}

// ---------------------------------------------------------------------------
// hidden: XH = f16(relu(samples @ W^T + b)), MFMA 32x32x16, 4 waves x 32 rows
// ---------------------------------------------------------------------------
__global__ __launch_bounds__(256, 2) void hidden_kernel(
    const float* __restrict__ A, const _Float16* __restrict__ WHsw,
    const float* __restrict__ bias, _Float16* __restrict__ XH)
{
    __shared__ __align__(16) _Float16 sW[2][32 * 256];
    __shared__ float sBias[256];
    const int t = threadIdx.x;
    const int wv = t >> 6, lane = t & 63, lid = lane & 31, h = lane >> 5;
    const int rowBase = blockIdx.x * 128 + wv * 32;
    const int swz = lid & 7;

    sBias[t] = bias[t];

    h8 xa[16];
    {
        const float* arow = A + (size_t)(rowBase + lid) * DD + 8 * h;
        #pragma unroll
        for (int kc = 0; kc < 16; ++kc) {
            float4 va = *(const float4*)(arow + kc * 16);
            float4 vb = *(const float4*)(arow + kc * 16 + 4);
            h8 x;
            x[0]=(_Float16)va.x; x[1]=(_Float16)va.y; x[2]=(_Float16)va.z; x[3]=(_Float16)va.w;
            x[4]=(_Float16)vb.x; x[5]=(_Float16)vb.y; x[6]=(_Float16)vb.z; x[7]=(_Float16)vb.w;
            xa[kc] = x;
        }
    }
    #pragma unroll
    for (int i = 0; i < 4; ++i)
        gll16(WHsw + (i * 256 + t) * 8, &sW[0][(i * 256 + t) * 8]);
    __syncthreads();

    #pragma unroll
    for (int ct = 0; ct < 8; ++ct) {
        const int buf = ct & 1;
        if (ct + 1 < 8) {
            const _Float16* g = WHsw + (size_t)(ct + 1) * 8192;
            #pragma unroll
            for (int i = 0; i < 4; ++i)
                gll16(g + (i * 256 + t) * 8, &sW[buf ^ 1][(i * 256 + t) * 8]);
        }
        f32x16 c0, c1;
        #pragma unroll
        for (int r = 0; r < 16; ++r) { c0[r] = 0.f; c1[r] = 0.f; }
        const _Float16* wrow = &sW[buf][lid * 256];
        #pragma unroll
        for (int kc = 0; kc < 16; kc += 2) {
            h8 b0 = *(const h8*)(wrow + (((kc    ) * 2 + h) ^ swz) * 8);
            h8 b1 = *(const h8*)(wrow + (((kc + 1) * 2 + h) ^ swz) * 8);
            c0 = __builtin_amdgcn_mfma_f32_32x32x16_f16(xa[kc],     b0, c0, 0, 0, 0);
            c1 = __builtin_amdgcn_mfma_f32_32x32x16_f16(xa[kc + 1], b1, c1, 0, 0, 0);
        }
        const float bv = sBias[ct * 32 + lid];
        #pragma unroll
        for (int r = 0; r < 16; ++r) {
            const int n = rowBase + (r & 3) + 8 * (r >> 2) + 4 * h;
            float v = c0[r] + c1[r] + bv;
            XH[(size_t)n * DD + ct * 32 + lid] = (_Float16)fmaxf(v, 0.f);
        }
        __syncthreads();
    }
}

// ---------------------------------------------------------------------------
// MFMA flash attention, SWAPPED operands (T12 structure):
//  QK: S^T = mfma(A=proto-frag, B=x-frag): lane = x-row, regs = 16 protos.
//      K augmented to 272: chunk 16 carries -|p|^2/2 (hi+lo), so logits
//      = 2*(x.p - p^2/2) need NO global/scalar loads in the loop -> the
//      counted vmcnt(10) pipeline is real (R4-R6 drained it via P2 loads).
//  softmax: per-lane in-register (max/sum over 16 regs + 1 shfl_xor(32));
//      unconditional online rescale (defer-max never defers at logit sigma~45).
//  PV: x~^T = mfma(A=PT-frag, B=P^T-frag): P^T assembled in-register via
//      cvt_pkrtz + 8 shfl_xor(32) + cndmask. No q LDS roundtrip.
//  Per wave-tile LDS: 17 QK + 16 PV b128 reads. 2 barriers/tile, vmcnt(10).
//  4 waves x 32 rows = 128 rows/block; LDS 80 KiB exactly -> 2 blocks/CU.
// ---------------------------------------------------------------------------
__global__ __launch_bounds__(256, 2) void attn_kernel(
    const _Float16* __restrict__ XH, const _Float16* __restrict__ PHsw,
    const _Float16* __restrict__ PTsw, _Float16* __restrict__ XT)
{
    __shared__ __align__(16) _Float16 sPH[2][32 * 320];   // 40 KiB
    __shared__ __align__(16) _Float16 sPT[2][256 * 40];   // 40 KiB

    const int t = threadIdx.x;
    const int lane = t & 63, lid = lane & 31, h = lane >> 5;
    const int rowBase = blockIdx.x * 128 + (t >> 6) * 32;
    const int sw3 = lid & 7;
    const float C2 = 2.8853900818f;   // 2 * log2(e)

    // x B-fragments (lane = x-row), plus augmented chunk {1,1,0,...} on h=0
    h8 xa[16], xaug;
    {
        const _Float16* xrow = XH + (size_t)(rowBase + lid) * DD + 8 * h;
        #pragma unroll
        for (int kc = 0; kc < 16; ++kc)
            xa[kc] = *(const h8*)(xrow + kc * 16);
        #pragma unroll
        for (int j = 0; j < 8; ++j) xaug[j] = (_Float16)0.f;
        if (h == 0) { xaug[0] = (_Float16)1.f; xaug[1] = (_Float16)1.f; }
    }

    f32x16 acc[8];
    #pragma unroll
    for (int f = 0; f < 8; ++f)
        #pragma unroll
        for (int r = 0; r < 16; ++r) acc[f][r] = 0.f;
    float m = -3e38f, l = 0.f;

    #define STAGE(tl, bf)                                                        \
    {                                                                            \
        const char* g0 = (const char*)(PHsw + (size_t)(tl) * 10240);             \
        const char* g2 = (const char*)(PTsw + (size_t)(tl) * 10240);             \
        char* d0 = (char*)&sPH[bf][0];                                           \
        char* d2 = (char*)&sPT[bf][0];                                           \
        _Pragma("unroll")                                                        \
        for (int i = 0; i < 5; ++i)                                              \
            gll16(g0 + i * 4096 + t * 16, d0 + i * 4096 + t * 16);               \
        _Pragma("unroll")                                                        \
        for (int i = 0; i < 5; ++i)                                              \
            gll16(g2 + i * 4096 + t * 16, d2 + i * 4096 + t * 16);               \
    }

    STAGE(0, 0);   // prologue: tile 0 in flight

    for (int tile = 0; tile < NT; ++tile) {
        const int buf = tile & 1;
        if (tile + 1 < NT) {
            STAGE(tile + 1, buf ^ 1);
            asm volatile("s_waitcnt vmcnt(10)" ::: "memory");  // this tile landed
        } else {
            asm volatile("s_waitcnt vmcnt(0)" ::: "memory");
        }
        __builtin_amdgcn_s_barrier();   // all waves' staging visible

        // ---- QK^T (swapped): S[reg=proto][lane=x-row], K=272 ----
        f32x16 S;
        #pragma unroll
        for (int r = 0; r < 16; ++r) S[r] = 0.f;
        {
            const _Float16* phrow = &sPH[buf][lid * 320];
            __builtin_amdgcn_s_setprio(1);
            #pragma unroll
            for (int kc = 0; kc < 16; ++kc) {
                h8 a = *(const h8*)(phrow + (((kc * 2 + h) ^ sw3) * 8));
                S = __builtin_amdgcn_mfma_f32_32x32x16_f16(a, xa[kc], S, 0, 0, 0);
            }
            {   // augmented chunk: adds -|p|^2/2 per proto row
                h8 a = *(const h8*)(phrow + 256 + ((h ^ sw3) * 8));
                S = __builtin_amdgcn_mfma_f32_32x32x16_f16(a, xaug, S, 0, 0, 0);
            }
            __builtin_amdgcn_s_setprio(0);
        }

        // ---- per-lane online softmax (lane owns x-row lid; regs = 16 protos,
        //      other 16 protos live in lane^32) ----
        float tmax = fmaxf(S[0], S[1]);
        #pragma unroll
        for (int r = 2; r < 16; ++r) tmax = fmaxf(tmax, S[r]);
        tmax = fmaxf(tmax, __shfl_xor(tmax, 32, 64));
        if (!__all(tmax <= m)) {
            float mn = fmaxf(m, tmax);
            float sc = exp2f((m - mn) * C2);
            m = mn; l *= sc;
            #pragma unroll
            for (int f = 0; f < 8; ++f) acc[f] *= sc;
        }
        float w[16];
        #pragma unroll
        for (int r = 0; r < 16; ++r) w[r] = exp2f((S[r] - m) * C2);
        {
            float sw = 0.f;
            #pragma unroll
            for (int r = 0; r < 16; ++r) sw += w[r];
            sw += __shfl_xor(sw, 32, 64);
            l += sw;
        }

        // ---- assemble P^T B-fragments in-register ----
        // reg r (half h) = proto (r&3)+8*(r>>2)+4h; pack pairs, exchange halves
        union { fp16x2 hh; int i; } cv[8];
        #pragma unroll
        for (int q = 0; q < 8; ++q)
            cv[q].hh = __builtin_amdgcn_cvt_pkrtz(w[2 * q], w[2 * q + 1]);
        int x01 = __shfl_xor(cv[0].i, 32, 64);
        int x23 = __shfl_xor(cv[1].i, 32, 64);
        int x45 = __shfl_xor(cv[2].i, 32, 64);
        int x67 = __shfl_xor(cv[3].i, 32, 64);
        int x89 = __shfl_xor(cv[4].i, 32, 64);
        int xAB = __shfl_xor(cv[5].i, 32, 64);
        int xCD = __shfl_xor(cv[6].i, 32, 64);
        int xEF = __shfl_xor(cv[7].i, 32, 64);
        union { int u[4]; h8 v; } B1, B2;
        B1.u[0] = h ? x45     : cv[0].i;   // protos (0,1)/(8,9)
        B1.u[1] = h ? x67     : cv[1].i;   // (2,3)/(10,11)
        B1.u[2] = h ? cv[2].i : x01;       // (4,5)/(12,13)
        B1.u[3] = h ? cv[3].i : x23;       // (6,7)/(14,15)
        B2.u[0] = h ? xCD     : cv[4].i;   // (16,17)/(24,25)
        B2.u[1] = h ? xEF     : cv[5].i;   // (18,19)/(26,27)
        B2.u[2] = h ? cv[6].i : x89;       // (20,21)/(28,29)
        B2.u[3] = h ? cv[7].i : xAB;       // (22,23)/(30,31)

        // ---- PV (swapped): acc[f][reg=dim][lane=x-row] ----
        {
            __builtin_amdgcn_s_setprio(1);
            #pragma unroll
            for (int f = 0; f < 8; ++f) {
                const _Float16* pt = &sPT[buf][(f * 32 + lid) * 40 + 8 * h];
                h8 a0 = *(const h8*)(pt);
                h8 a1 = *(const h8*)(pt + 16);
                acc[f] = __builtin_amdgcn_mfma_f32_32x32x16_f16(a0, B1.v, acc[f], 0, 0, 0);
                acc[f] = __builtin_amdgcn_mfma_f32_32x32x16_f16(a1, B2.v, acc[f], 0, 0, 0);
            }
            __builtin_amdgcn_s_setprio(0);
        }
        asm volatile("s_waitcnt lgkmcnt(0)" ::: "memory");  // LDS reads retired
        __builtin_amdgcn_s_barrier();    // gate buffer overwrite next iter
    }
    #undef STAGE

    // ---- epilogue: x_tilde[row=lid][dim] = acc/l, packed 4xf16 stores ----
    {
        const float inv = 1.f / l;
        _Float16* xrow = XT + (size_t)(rowBase + lid) * DD;
        #pragma unroll
        for (int f = 0; f < 8; ++f) {
            #pragma unroll
            for (int g = 0; g < 4; ++g) {
                union { fp16x2 hh[2]; uint2 u; } U;
                U.hh[0] = __builtin_amdgcn_cvt_pkrtz(acc[f][4 * g + 0] * inv,
                                                     acc[f][4 * g + 1] * inv);
                U.hh[1] = __builtin_amdgcn_cvt_pkrtz(acc[f][4 * g + 2] * inv,
                                                     acc[f][4 * g + 3] * inv);
                *(uint2*)(xrow + f * 32 + 8 * g + 4 * h) = U.u;
            }
        }
    }
}

// ---------------------------------------------------------------------------
// out: OUT[n][c] = [x | x_tilde] @ OW^T, MFMA, K=512, cols padded to 128
// ---------------------------------------------------------------------------
__global__ __launch_bounds__(256, 2) void out_kernel(
    const _Float16* __restrict__ XH, const _Float16* __restrict__ XT,
    const _Float16* __restrict__ OWsw, float* __restrict__ OUT)
{
    __shared__ __align__(16) _Float16 sW[2][32 * 256];
    const int t = threadIdx.x;
    const int wv = t >> 6, lane = t & 63, lid = lane & 31, h = lane >> 5;
    const int rowBase = blockIdx.x * 128 + wv * 32;
    const int swz = lid & 7;

    h8 xa[32];
    {
        const _Float16* x0 = XH + (size_t)(rowBase + lid) * DD + 8 * h;
        const _Float16* x1 = XT + (size_t)(rowBase + lid) * DD + 8 * h;
        #pragma unroll
        for (int kc = 0; kc < 16; ++kc) xa[kc]      = *(const h8*)(x0 + kc * 16);
        #pragma unroll
        for (int kc = 0; kc < 16; ++kc) xa[16 + kc] = *(const h8*)(x1 + kc * 16);
    }

    f32x16 acc[4];
    #pragma unroll
    for (int q = 0; q < 4; ++q)
        #pragma unroll
        for (int r = 0; r < 16; ++r) acc[q][r] = 0.f;

    #pragma unroll
    for (int i = 0; i < 4; ++i)
        gll16(OWsw + (i * 256 + t) * 8, &sW[0][(i * 256 + t) * 8]);
    __syncthreads();

    #pragma unroll
    for (int ch = 0; ch < 8; ++ch) {
        const int buf = ch & 1;
        if (ch + 1 < 8) {
            const _Float16* g = OWsw + (size_t)(ch + 1) * 8192;
            #pragma unroll
            for (int i = 0; i < 4; ++i)
                gll16(g + (i * 256 + t) * 8, &sW[buf ^ 1][(i * 256 + t) * 8]);
        }
        const int ct = ch >> 1, kh = ch & 1;
        const _Float16* wrow = &sW[buf][lid * 256];
        f32x16 a = acc[ct];
        #pragma unroll
        for (int kc = 0; kc < 16; ++kc) {
            h8 b = *(const h8*)(wrow + ((kc * 2 + h) ^ swz) * 8);
            a = __builtin_amdgcn_mfma_f32_32x32x16_f16(xa[kh * 16 + kc], b, a, 0, 0, 0);
        }
        acc[ct] = a;
        __syncthreads();
    }

    #pragma unroll
    for (int ct = 0; ct < 4; ++ct) {
        const int col = ct * 32 + lid;
        if (col < NCLSS) {
            #pragma unroll
            for (int r = 0; r < 16; ++r) {
                const int n = rowBase + (r & 3) + 8 * (r >> 2) + 4 * h;
                OUT[(size_t)n * NCLSS + col] = acc[ct][r];
            }
        }
    }
}

// ---------------------------------------------------------------------------
extern "C" void kernel_launch(void* const* d_in, const int* in_sizes, int n_in,
                              void* d_out, int out_size, void* d_ws, size_t ws_size,
                              hipStream_t stream) {
    const float* samples  = (const float*)d_in[0];
    const float* hidden_w = (const float*)d_in[1];
    const float* hidden_b = (const float*)d_in[2];
    const float* protos   = (const float*)d_in[3];
    const float* output_w = (const float*)d_in[4];
    float* out = (float*)d_out;

    char* ws = (char*)d_ws;
    _Float16* XH   = (_Float16*)(ws);                  // 26,214,400
    _Float16* XT   = (_Float16*)(ws + 26214400);       // 26,214,400
    _Float16* PHsw = (_Float16*)(ws + 52428800);       // 63*20480 = 1,290,240
    _Float16* PTsw = (_Float16*)(ws + 53719040);       // 63*20480 = 1,290,240
    _Float16* WHsw = (_Float16*)(ws + 55009280);       // 131,072
    _Float16* OWsw = (_Float16*)(ws + 55140352);       // 131,072
    float*    P2   = (float*)   (ws + 55271424);       // 8,064

    p2_kernel <<<8,   256, 0, stream>>>(protos, P2);
    prep_proto<<<252, 256, 0, stream>>>(protos, P2, PHsw, PTsw);
    prep_w    <<<32,  256, 0, stream>>>(hidden_w, WHsw);
    prep_ow   <<<32,  256, 0, stream>>>(output_w, OWsw);
    hidden_kernel<<<400, 256, 0, stream>>>(samples, WHsw, hidden_b, XH);
    attn_kernel  <<<400, 256, 0, stream>>>(XH, PHsw, PTsw, XT);
    out_kernel   <<<400, 256, 0, stream>>>(XH, XT, OWsw, out);
}